// Round 3
// baseline (8298.566 us; speedup 1.0000x reference)
//
#include <hip/hip_runtime.h>
#include <math.h>

#define BB 2048
#define TT 64
#define MM 256
#define PP 256

// ---------------------------------------------------------------------------
// Tiled GEMM: C[M x N] = A[M x K] @ W[N x K]^T (+ bias[N])
// 64x64 tile per 256-thread block, each thread computes 4x4 outputs.
// Used only for the big one-time Ue precompute (8192 blocks).
// ---------------------------------------------------------------------------
__global__ __launch_bounds__(256) void gemm64(
    const float* __restrict__ A, int lda,
    const float* __restrict__ W, int ldw,
    const float* __restrict__ bias,
    float* __restrict__ C, int ldc,
    int K)
{
    __shared__ float As[64][36];
    __shared__ float Ws[64][36];

    const int tid = threadIdx.x;
    const int row0 = blockIdx.x * 64;
    const int col0 = blockIdx.y * 64;

    const int lr = tid >> 3;
    const int lc4 = (tid & 7) * 4;
    const int tx = tid & 15;
    const int ty = tid >> 4;

    float acc[4][4] = {{0.f}};

    for (int k0 = 0; k0 < K; k0 += 32) {
        const float4 a0 = *(const float4*)&A[(size_t)(row0 + lr) * lda + k0 + lc4];
        const float4 a1 = *(const float4*)&A[(size_t)(row0 + lr + 32) * lda + k0 + lc4];
        const float4 w0 = *(const float4*)&W[(size_t)(col0 + lr) * ldw + k0 + lc4];
        const float4 w1 = *(const float4*)&W[(size_t)(col0 + lr + 32) * ldw + k0 + lc4];
        *(float4*)&As[lr][lc4] = a0;
        *(float4*)&As[lr + 32][lc4] = a1;
        *(float4*)&Ws[lr][lc4] = w0;
        *(float4*)&Ws[lr + 32][lc4] = w1;
        __syncthreads();

        #pragma unroll
        for (int kk = 0; kk < 32; kk += 4) {
            float4 a[4], w[4];
            #pragma unroll
            for (int i = 0; i < 4; i++) a[i] = *(const float4*)&As[ty + 16 * i][kk];
            #pragma unroll
            for (int j = 0; j < 4; j++) w[j] = *(const float4*)&Ws[tx + 16 * j][kk];
            #pragma unroll
            for (int i = 0; i < 4; i++)
                #pragma unroll
                for (int j = 0; j < 4; j++) {
                    acc[i][j] += a[i].x * w[j].x;
                    acc[i][j] += a[i].y * w[j].y;
                    acc[i][j] += a[i].z * w[j].z;
                    acc[i][j] += a[i].w * w[j].w;
                }
        }
        __syncthreads();
    }

    #pragma unroll
    for (int i = 0; i < 4; i++) {
        const int rr = row0 + ty + 16 * i;
        #pragma unroll
        for (int j = 0; j < 4; j++) {
            const int cc = col0 + tx + 16 * j;
            float v = acc[i][j];
            if (bias) v += bias[cc];
            C[(size_t)rr * ldc + cc] = v;
        }
    }
}

// ---------------------------------------------------------------------------
// 32x32 LDS-tiled transpose: out[C][R] = in[R][C]^T. grid (C/32, R/32), 256 thr.
// ---------------------------------------------------------------------------
__global__ __launch_bounds__(256) void transpose32(
    const float* __restrict__ in, float* __restrict__ out, int R, int C)
{
    __shared__ float t[32][33];
    const int cb = blockIdx.x * 32, rb = blockIdx.y * 32;
    const int tx = threadIdx.x & 31, ty0 = (threadIdx.x >> 5) * 4;
    #pragma unroll
    for (int i = 0; i < 4; i++)
        t[ty0 + i][tx] = in[(size_t)(rb + ty0 + i) * C + cb + tx];
    __syncthreads();
    #pragma unroll
    for (int i = 0; i < 4; i++)
        out[(size_t)(cb + ty0 + i) * R + rb + tx] = t[tx][ty0 + i];
}

// ---------------------------------------------------------------------------
// Fused state step. Each block owns 8 batch rows exclusively (no races).
//  phase 1: LSTM update (h,c) from gates_in + ytl  -> ds + LDS
//  phase 2: x1[b][:]    = [h,c] @ W_d^T + b_d      (K=512)
//  phase 3: gates_out   = h @ W_hh^T               (K=256, via WhhT)
// first=1: treat state as zeros (initial step), skip LSTM math.
// ---------------------------------------------------------------------------
__global__ __launch_bounds__(256) void state_step(
    const float* __restrict__ gates_in, // [B][1024]
    const float* __restrict__ ytl,      // [B]
    const float* __restrict__ W_ih,     // [1024]
    const float* __restrict__ b_ih,     // [1024]
    const float* __restrict__ b_hh,     // [1024]
    const float* __restrict__ W_d_w,    // [256][512] row-major
    const float* __restrict__ W_d_b,    // [256]
    const float* __restrict__ WhhT,     // [256][1024] (W_hh transposed)
    float* __restrict__ ds,             // [B][512] h|c
    float* __restrict__ x1,             // [B][256]
    float* __restrict__ gates_out,      // [B][1024]
    int first)
{
    const int tid = threadIdx.x;
    const int b0 = blockIdx.x * 8;

    __shared__ float hc[8][512];

    // ---- phase 1: LSTM elementwise update, thread owns channel p=tid ----
    #pragma unroll
    for (int r = 0; r < 8; r++) {
        const int b = b0 + r;
        float h, c;
        if (first) {
            h = 0.f; c = 0.f;
        } else {
            const float x = ytl[b];
            const float* g = gates_in + (size_t)b * 1024;
            const float gi = g[tid]       + x * W_ih[tid]       + b_ih[tid]       + b_hh[tid];
            const float gf = g[tid + 256] + x * W_ih[tid + 256] + b_ih[tid + 256] + b_hh[tid + 256];
            const float gg = g[tid + 512] + x * W_ih[tid + 512] + b_ih[tid + 512] + b_hh[tid + 512];
            const float go = g[tid + 768] + x * W_ih[tid + 768] + b_ih[tid + 768] + b_hh[tid + 768];
            const float c_old = ds[(size_t)b * 512 + 256 + tid];
            const float si = 1.f / (1.f + __expf(-gi));
            const float sf = 1.f / (1.f + __expf(-gf));
            const float so = 1.f / (1.f + __expf(-go));
            c = sf * c_old + si * tanhf(gg);
            h = so * tanhf(c);
        }
        hc[r][tid] = h;
        hc[r][256 + tid] = c;
        ds[(size_t)b * 512 + tid] = h;
        ds[(size_t)b * 512 + 256 + tid] = c;
    }
    __syncthreads();

    // ---- phase 2: x1, thread owns output col n=tid for all 8 rows ----
    {
        float acc[8] = {0.f, 0.f, 0.f, 0.f, 0.f, 0.f, 0.f, 0.f};
        const float* wrow = W_d_w + (size_t)tid * 512;
        for (int k0 = 0; k0 < 512; k0 += 4) {
            const float4 w = *(const float4*)&wrow[k0];
            #pragma unroll
            for (int r = 0; r < 8; r++) {
                const float4 hv = *(const float4*)&hc[r][k0];
                acc[r] += hv.x * w.x + hv.y * w.y + hv.z * w.z + hv.w * w.w;
            }
        }
        const float bias = W_d_b[tid];
        #pragma unroll
        for (int r = 0; r < 8; r++)
            x1[(size_t)(b0 + r) * 256 + tid] = acc[r] + bias;
    }

    // ---- phase 3: gates_out, thread owns cols {tid, tid+256, tid+512, tid+768} ----
    {
        float acc[8][4];
        #pragma unroll
        for (int r = 0; r < 8; r++)
            #pragma unroll
            for (int j = 0; j < 4; j++) acc[r][j] = 0.f;

        for (int k = 0; k < 256; k++) {
            const float* wk = WhhT + (size_t)k * 1024;
            const float wa = wk[tid];
            const float wb = wk[tid + 256];
            const float wc = wk[tid + 512];
            const float wd = wk[tid + 768];
            #pragma unroll
            for (int r = 0; r < 8; r++) {
                const float hv = hc[r][k];
                acc[r][0] += hv * wa;
                acc[r][1] += hv * wb;
                acc[r][2] += hv * wc;
                acc[r][3] += hv * wd;
            }
        }
        #pragma unroll
        for (int r = 0; r < 8; r++) {
            float* go = gates_out + (size_t)(b0 + r) * 1024;
            #pragma unroll
            for (int j = 0; j < 4; j++)
                go[j * 256 + tid] = acc[r][j];
        }
    }
}

// ---------------------------------------------------------------------------
// Attention step (unchanged from baseline): per block b.
// ---------------------------------------------------------------------------
__global__ __launch_bounds__(256) void attention_step(
    const float* __restrict__ Ue,       // [B*T][M]
    const float* __restrict__ enc,      // [B*T][M]
    const float* __restrict__ x1,       // [B][M]
    const float* __restrict__ v_d,      // [M]
    const float* __restrict__ w_tilda_w,// [M+1]
    const float* __restrict__ w_tilda_b,// [1]
    const float* __restrict__ y,        // [B][T]
    int t_step,
    float* __restrict__ c_t,            // [B][M]
    float* __restrict__ beta_out,       // [B][T]
    float* __restrict__ y_tilda)        // [B]
{
    const int b = blockIdx.x;
    const int tid = threadIdx.x;
    const int lane = tid & 63;
    const int wv = tid >> 6;

    __shared__ float xs[MM];
    __shared__ float lt[TT];
    __shared__ float red[4];

    xs[tid] = x1[(size_t)b * MM + tid];
    __syncthreads();

    for (int tt = wv; tt < TT; tt += 4) {
        const float* Urow = Ue + ((size_t)b * TT + tt) * MM;
        float s = 0.f;
        #pragma unroll
        for (int q = 0; q < 4; q++) {
            const int m = lane + q * 64;
            s += v_d[m] * tanhf(xs[m] + Urow[m]);
        }
        #pragma unroll
        for (int off = 32; off > 0; off >>= 1) s += __shfl_down(s, off);
        if (lane == 0) lt[tt] = s;
    }
    __syncthreads();

    if (wv == 0) {
        float v = lt[lane];
        float mx = v;
        #pragma unroll
        for (int off = 32; off > 0; off >>= 1) mx = fmaxf(mx, __shfl_xor(mx, off));
        const float e = __expf(v - mx);
        float sm = e;
        #pragma unroll
        for (int off = 32; off > 0; off >>= 1) sm += __shfl_xor(sm, off);
        const float bta = e / sm;
        lt[lane] = bta;
        beta_out[(size_t)b * TT + lane] = bta;
    }
    __syncthreads();

    float cv = 0.f;
    const float* erow = enc + (size_t)b * TT * MM + tid;
    #pragma unroll 8
    for (int tt = 0; tt < TT; tt++) cv += lt[tt] * erow[(size_t)tt * MM];
    c_t[(size_t)b * MM + tid] = cv;

    float contrib = w_tilda_w[tid] * cv;
    #pragma unroll
    for (int off = 32; off > 0; off >>= 1) contrib += __shfl_down(contrib, off);
    if (lane == 0) red[wv] = contrib;
    __syncthreads();
    if (tid == 0) {
        float s = red[0] + red[1] + red[2] + red[3];
        s += w_tilda_w[MM] * y[(size_t)b * TT + t_step] + w_tilda_b[0];
        y_tilda[b] = s;
    }
}

// ---------------------------------------------------------------------------
// Final head: y = v_y . ( [d, c_t] @ W_y^T + b_y ) + v_y_b
// ---------------------------------------------------------------------------
__global__ __launch_bounds__(256) void final_out(
    const float* __restrict__ ds,     // [B][512] (h part = d)
    const float* __restrict__ c_t,    // [B][256]
    const float* __restrict__ W_y_w,  // [256][512]
    const float* __restrict__ W_y_b,  // [256]
    const float* __restrict__ v_y_w,  // [256]
    const float* __restrict__ v_y_b,  // [1]
    float* __restrict__ out)          // [B]
{
    const int b = blockIdx.x;
    const int tid = threadIdx.x;
    const int lane = tid & 63;
    const int wv = tid >> 6;

    __shared__ float dc[512];
    __shared__ float red[4];

    dc[tid] = ds[(size_t)b * 512 + tid];
    dc[256 + tid] = c_t[(size_t)b * 256 + tid];
    __syncthreads();

    float acc = W_y_b[tid];
    const float* wr = W_y_w + (size_t)tid * 512;
    #pragma unroll 8
    for (int k = 0; k < 512; k++) acc += dc[k] * wr[k];

    float contrib = acc * v_y_w[tid];
    #pragma unroll
    for (int off = 32; off > 0; off >>= 1) contrib += __shfl_down(contrib, off);
    if (lane == 0) red[wv] = contrib;
    __syncthreads();
    if (tid == 0) out[b] = red[0] + red[1] + red[2] + red[3] + v_y_b[0];
}

// ---------------------------------------------------------------------------
extern "C" void kernel_launch(void* const* d_in, const int* in_sizes, int n_in,
                              void* d_out, int out_size, void* d_ws, size_t ws_size,
                              hipStream_t stream)
{
    const float* enc      = (const float*)d_in[0];   // [B,T,M]
    const float* y        = (const float*)d_in[1];   // [B,T,1]
    const float* W_d_w    = (const float*)d_in[2];   // [256,512]
    const float* W_d_b    = (const float*)d_in[3];   // [256]
    const float* U_d_w    = (const float*)d_in[4];   // [256,256]
    const float* v_d_w    = (const float*)d_in[5];   // [256]
    const float* w_tilda_w= (const float*)d_in[6];   // [257]
    const float* w_tilda_b= (const float*)d_in[7];   // [1]
    const float* W_y_w    = (const float*)d_in[8];   // [256,512]
    const float* W_y_b    = (const float*)d_in[9];   // [256]
    const float* v_y_w    = (const float*)d_in[10];  // [256]
    const float* v_y_b    = (const float*)d_in[11];  // [1]
    const float* W_ih     = (const float*)d_in[12];  // [1024]
    const float* W_hh     = (const float*)d_in[13];  // [1024,256]
    const float* b_ih     = (const float*)d_in[14];  // [1024]
    const float* b_hh     = (const float*)d_in[15];  // [1024]

    float* out = (float*)d_out;          // y_Tp1 [2048] then beta [2048*64]

    float* Ue    = (float*)d_ws;                     // 33,554,432 floats
    float* ds    = Ue + (size_t)BB * TT * MM;        //  1,048,576
    float* x1v   = ds + (size_t)BB * 512;            //    524,288
    float* ctv   = x1v + (size_t)BB * MM;            //    524,288
    float* gates = ctv + (size_t)BB * MM;            //  2,097,152
    float* ytl   = gates + (size_t)BB * 4 * PP;      //      2,048
    float* WhhT  = ytl + BB;                         //    262,144

    hipMemsetAsync(ds, 0, (size_t)BB * 512 * sizeof(float), stream);

    // WhhT[256][1024] = W_hh[1024][256]^T
    transpose32<<<dim3(256 / 32, 1024 / 32), 256, 0, stream>>>(W_hh, WhhT, 1024, 256);

    // Ue = enc @ U_d^T   [131072 x 256]
    gemm64<<<dim3(BB * TT / 64, MM / 64), 256, 0, stream>>>(
        enc, MM, U_d_w, MM, nullptr, Ue, MM, MM);

    // initial state step: h=c=0 -> x1(0)=b_d, gates(0)=0
    state_step<<<BB / 8, 256, 0, stream>>>(
        gates, ytl, W_ih, b_ih, b_hh, W_d_w, W_d_b, WhhT, ds, x1v, gates, 1);

    for (int t = 0; t < TT; t++) {
        attention_step<<<BB, 256, 0, stream>>>(
            Ue, enc, x1v, v_d_w, w_tilda_w, w_tilda_b, y, t, ctv, out + BB, ytl);
        state_step<<<BB / 8, 256, 0, stream>>>(
            gates, ytl, W_ih, b_ih, b_hh, W_d_w, W_d_b, WhhT, ds, x1v, gates, 0);
    }

    final_out<<<BB, 256, 0, stream>>>(ds, ctv, W_y_w, W_y_b, v_y_w, v_y_b, out);
}

// Round 4
// 6790.717 us; speedup vs baseline: 1.2220x; 1.2220x over previous
//
#include <hip/hip_runtime.h>
#include <math.h>

#define BB 2048
#define TT 64
#define MM 256

typedef __attribute__((ext_vector_type(8))) unsigned short u16x8;

__device__ __forceinline__ float bf2f(unsigned short u) {
    union { unsigned int i; float f; } v; v.i = ((unsigned int)u) << 16; return v.f;
}
__device__ __forceinline__ unsigned short f2bf(float f) {
    union { float f; unsigned int i; } v; v.f = f;
    const unsigned int r = v.i + 0x7fff + ((v.i >> 16) & 1);  // RNE
    return (unsigned short)(r >> 16);
}

// ---------------------------------------------------------------------------
// Tiled GEMM with bf16 output: C[M x N] = A[M x K] @ W[N x K]^T  (Ue precompute)
// ---------------------------------------------------------------------------
__global__ __launch_bounds__(256) void gemm64_bf(
    const float* __restrict__ A, int lda,
    const float* __restrict__ W, int ldw,
    unsigned short* __restrict__ C, int ldc, int K)
{
    __shared__ float As[64][36];
    __shared__ float Ws[64][36];

    const int tid = threadIdx.x;
    const int row0 = blockIdx.x * 64;
    const int col0 = blockIdx.y * 64;

    const int lr = tid >> 3;
    const int lc4 = (tid & 7) * 4;
    const int tx = tid & 15;
    const int ty = tid >> 4;

    float acc[4][4] = {{0.f}};

    for (int k0 = 0; k0 < K; k0 += 32) {
        const float4 a0 = *(const float4*)&A[(size_t)(row0 + lr) * lda + k0 + lc4];
        const float4 a1 = *(const float4*)&A[(size_t)(row0 + lr + 32) * lda + k0 + lc4];
        const float4 w0 = *(const float4*)&W[(size_t)(col0 + lr) * ldw + k0 + lc4];
        const float4 w1 = *(const float4*)&W[(size_t)(col0 + lr + 32) * ldw + k0 + lc4];
        *(float4*)&As[lr][lc4] = a0;
        *(float4*)&As[lr + 32][lc4] = a1;
        *(float4*)&Ws[lr][lc4] = w0;
        *(float4*)&Ws[lr + 32][lc4] = w1;
        __syncthreads();

        #pragma unroll
        for (int kk = 0; kk < 32; kk += 4) {
            float4 a[4], w[4];
            #pragma unroll
            for (int i = 0; i < 4; i++) a[i] = *(const float4*)&As[ty + 16 * i][kk];
            #pragma unroll
            for (int j = 0; j < 4; j++) w[j] = *(const float4*)&Ws[tx + 16 * j][kk];
            #pragma unroll
            for (int i = 0; i < 4; i++)
                #pragma unroll
                for (int j = 0; j < 4; j++) {
                    acc[i][j] += a[i].x * w[j].x;
                    acc[i][j] += a[i].y * w[j].y;
                    acc[i][j] += a[i].z * w[j].z;
                    acc[i][j] += a[i].w * w[j].w;
                }
        }
        __syncthreads();
    }

    #pragma unroll
    for (int i = 0; i < 4; i++) {
        const int rr = row0 + ty + 16 * i;
        #pragma unroll
        for (int j = 0; j < 4; j++)
            C[(size_t)rr * ldc + col0 + tx + 16 * j] = f2bf(acc[i][j]);
    }
}

// ---------------------------------------------------------------------------
// fp32 -> bf16 convert (enc)
// ---------------------------------------------------------------------------
__global__ __launch_bounds__(256) void cvt_bf16(
    const float* __restrict__ in, unsigned short* __restrict__ out, int n4)
{
    int i = blockIdx.x * 256 + threadIdx.x;
    const int stride = gridDim.x * 256;
    for (; i < n4; i += stride) {
        const float4 v = ((const float4*)in)[i];
        ushort4 o;
        o.x = f2bf(v.x); o.y = f2bf(v.y); o.z = f2bf(v.z); o.w = f2bf(v.w);
        ((ushort4*)out)[i] = o;
    }
}

// ---------------------------------------------------------------------------
// Persistent fused decoder: 256 blocks x 512 threads, block owns 8 batch rows
// for the full 64-step recurrence. All state in LDS; global traffic in the
// loop = bf16 Ue/enc streams + fp32 weight streams only.
// ---------------------------------------------------------------------------
__global__ __launch_bounds__(512) void fused_decoder(
    const unsigned short* __restrict__ Ue,   // [B][T][M] bf16
    const unsigned short* __restrict__ encb, // [B][T][M] bf16
    const float* __restrict__ y,             // [B][T]
    const float* __restrict__ W_d_w,         // [256][512]
    const float* __restrict__ W_d_b,         // [256]
    const float* __restrict__ v_d,           // [256]
    const float* __restrict__ w_t_w,         // [257]
    const float* __restrict__ w_t_b,         // [1]
    const float* __restrict__ W_ih,          // [1024]
    const float* __restrict__ W_hh,          // [1024][256]
    const float* __restrict__ b_ih,          // [1024]
    const float* __restrict__ b_hh,          // [1024]
    const float* __restrict__ W_y_w,         // [256][512]
    const float* __restrict__ W_y_b,         // [256]
    const float* __restrict__ v_y_w,         // [256]
    const float* __restrict__ v_y_b,         // [1]
    float* __restrict__ out)                 // [2048 y_Tp1 | 2048*64 beta]
{
    const int tid = threadIdx.x;
    const int b0 = blockIdx.x * 8;

    __shared__ __align__(16) float hc[8][512];     // h | c per row
    __shared__ float gates[8][1024];               // h @ W_hh^T (no x/bias part)
    __shared__ float x1s[8][256];
    __shared__ float betas[8][64];
    __shared__ float ytl[8];
    __shared__ __align__(16) float ctx[8][256];
    __shared__ float vds[256];
    __shared__ float wtw[256];
    __shared__ float wihs[1024];
    __shared__ float bsums[1024];
    __shared__ float red[4][8];

    // ---- init ----
    if (tid < 256) {
        vds[tid] = v_d[tid];
        wtw[tid] = w_t_w[tid];
        const float bd = W_d_b[tid];
        #pragma unroll
        for (int r = 0; r < 8; r++) {
            x1s[r][tid] = bd;               // x1(0) = [0,0]@W_d^T + b_d
            hc[r][tid] = 0.f;
            hc[r][256 + tid] = 0.f;
        }
    }
    for (int i = tid; i < 1024; i += 512) {
        wihs[i] = W_ih[i];
        bsums[i] = b_ih[i] + b_hh[i];
    }
    for (int i = tid; i < 8 * 1024; i += 512) ((float*)gates)[i] = 0.f;

    const float wty = w_t_w[256];
    const float wtb = w_t_b[0];

    const int r_a = tid >> 6;       // wave id = row
    const int t_a = tid & 63;       // lane = t'
    const int m0b = (tid & 63) * 4;

    __syncthreads();

    for (int t = 0; t < TT; t++) {
        // ---- phase A: scores l[r][t'] + softmax (one wave per row) ----
        {
            const unsigned short* __restrict__ up =
                Ue + ((size_t)(b0 + r_a) * TT + t_a) * MM;
            float s = 0.f;
            #pragma unroll 2
            for (int m = 0; m < 256; m += 8) {
                const u16x8 u = *(const u16x8*)(up + m);
                #pragma unroll
                for (int j = 0; j < 8; j++)
                    s += vds[m + j] * tanhf(x1s[r_a][m + j] + bf2f(u[j]));
            }
            float mx = s;
            #pragma unroll
            for (int off = 32; off > 0; off >>= 1) mx = fmaxf(mx, __shfl_xor(mx, off));
            const float e = __expf(s - mx);
            float sm = e;
            #pragma unroll
            for (int off = 32; off > 0; off >>= 1) sm += __shfl_xor(sm, off);
            const float bta = e / sm;
            betas[r_a][t_a] = bta;                              // wave-local
            if (t == TT - 1) out[BB + (size_t)(b0 + r_a) * TT + t_a] = bta;
        }

        // ---- phase B: context + y_tilda (same wave->row mapping) ----
        {
            const unsigned short* __restrict__ ep =
                encb + (size_t)(b0 + r_a) * TT * MM + m0b;
            float c0 = 0.f, c1 = 0.f, c2 = 0.f, c3 = 0.f;
            #pragma unroll 4
            for (int tt2 = 0; tt2 < TT; tt2++) {
                const ushort4 u = *(const ushort4*)(ep + (size_t)tt2 * MM);
                const float bta = betas[r_a][tt2];
                c0 += bta * bf2f(u.x);
                c1 += bta * bf2f(u.y);
                c2 += bta * bf2f(u.z);
                c3 += bta * bf2f(u.w);
            }
            float part = wtw[m0b] * c0 + wtw[m0b + 1] * c1
                       + wtw[m0b + 2] * c2 + wtw[m0b + 3] * c3;
            #pragma unroll
            for (int off = 32; off > 0; off >>= 1) part += __shfl_down(part, off);
            if (t_a == 0)
                ytl[r_a] = part + wty * y[(size_t)(b0 + r_a) * TT + t] + wtb;
            if (t == TT - 1) {
                ctx[r_a][m0b]     = c0;
                ctx[r_a][m0b + 1] = c1;
                ctx[r_a][m0b + 2] = c2;
                ctx[r_a][m0b + 3] = c3;
            }
        }
        __syncthreads();   // ytl (and ctx at t=63) visible

        // ---- phase C1: LSTM elementwise update ----
        {
            const int p = tid & 255;
            const int half = tid >> 8;
            #pragma unroll
            for (int j = 0; j < 4; j++) {
                const int r = half * 4 + j;
                const float x = ytl[r];
                const float gi = gates[r][p]       + x * wihs[p]       + bsums[p];
                const float gf = gates[r][p + 256] + x * wihs[p + 256] + bsums[p + 256];
                const float gg = gates[r][p + 512] + x * wihs[p + 512] + bsums[p + 512];
                const float go = gates[r][p + 768] + x * wihs[p + 768] + bsums[p + 768];
                const float c_old = hc[r][256 + p];
                const float si = 1.f / (1.f + __expf(-gi));
                const float sf = 1.f / (1.f + __expf(-gf));
                const float so = 1.f / (1.f + __expf(-go));
                const float cn = sf * c_old + si * tanhf(gg);
                hc[r][p] = so * tanhf(cn);
                hc[r][256 + p] = cn;
            }
        }
        __syncthreads();   // new h|c visible; old gates fully consumed

        // ---- phase C2 (waves 0-3): x1 = [h,c] @ W_d^T + b_d ----
        if (tid < 256) {
            const int n = tid;
            const float* __restrict__ wr = W_d_w + (size_t)n * 512;
            float acc[8];
            #pragma unroll
            for (int r = 0; r < 8; r++) acc[r] = 0.f;
            #pragma unroll 2
            for (int k = 0; k < 512; k += 4) {
                const float4 w = *(const float4*)(wr + k);
                #pragma unroll
                for (int r = 0; r < 8; r++) {
                    const float4 h4 = *(const float4*)&hc[r][k];
                    acc[r] += w.x * h4.x + w.y * h4.y + w.z * h4.z + w.w * h4.w;
                }
            }
            const float bd = W_d_b[n];
            #pragma unroll
            for (int r = 0; r < 8; r++) x1s[r][n] = acc[r] + bd;
        }
        // ---- phase C3 (waves 4-7): gates = h @ W_hh^T ----
        else {
            const int n = tid - 256;
            const float* __restrict__ w0 = W_hh + (size_t)n * 256;
            const float* __restrict__ w1 = w0 + 256 * 256;
            const float* __restrict__ w2 = w0 + 512 * 256;
            const float* __restrict__ w3 = w0 + 768 * 256;
            float a0[8], a1[8], a2[8], a3[8];
            #pragma unroll
            for (int r = 0; r < 8; r++) { a0[r] = 0.f; a1[r] = 0.f; a2[r] = 0.f; a3[r] = 0.f; }
            #pragma unroll 2
            for (int k = 0; k < 256; k += 4) {
                const float4 q0 = *(const float4*)(w0 + k);
                const float4 q1 = *(const float4*)(w1 + k);
                const float4 q2 = *(const float4*)(w2 + k);
                const float4 q3 = *(const float4*)(w3 + k);
                #pragma unroll
                for (int r = 0; r < 8; r++) {
                    const float4 h4 = *(const float4*)&hc[r][k];
                    a0[r] += q0.x * h4.x + q0.y * h4.y + q0.z * h4.z + q0.w * h4.w;
                    a1[r] += q1.x * h4.x + q1.y * h4.y + q1.z * h4.z + q1.w * h4.w;
                    a2[r] += q2.x * h4.x + q2.y * h4.y + q2.z * h4.z + q2.w * h4.w;
                    a3[r] += q3.x * h4.x + q3.y * h4.y + q3.z * h4.z + q3.w * h4.w;
                }
            }
            #pragma unroll
            for (int r = 0; r < 8; r++) {
                gates[r][n]       = a0[r];
                gates[r][n + 256] = a1[r];
                gates[r][n + 512] = a2[r];
                gates[r][n + 768] = a3[r];
            }
        }
        __syncthreads();   // x1s + gates ready for next step
    }

    // ---- final head: out[r] = v_y . (W_y @ [h|ctx] + b_y) + v_y_b ----
    if (tid < 256) {
        const int n = tid;
        const float* __restrict__ wr = W_y_w + (size_t)n * 512;
        float acc[8];
        #pragma unroll
        for (int r = 0; r < 8; r++) acc[r] = 0.f;
        #pragma unroll 2
        for (int k = 0; k < 256; k += 4) {
            const float4 wh = *(const float4*)(wr + k);
            const float4 wc = *(const float4*)(wr + 256 + k);
            #pragma unroll
            for (int r = 0; r < 8; r++) {
                const float4 h4 = *(const float4*)&hc[r][k];
                const float4 c4 = *(const float4*)&ctx[r][k];
                acc[r] += wh.x * h4.x + wh.y * h4.y + wh.z * h4.z + wh.w * h4.w
                        + wc.x * c4.x + wc.y * c4.y + wc.z * c4.z + wc.w * c4.w;
            }
        }
        const float vy = v_y_w[n];
        const float by = W_y_b[n];
        const int wv = tid >> 6;
        const int lane = tid & 63;
        #pragma unroll
        for (int r = 0; r < 8; r++) {
            float v = (acc[r] + by) * vy;
            #pragma unroll
            for (int off = 32; off > 0; off >>= 1) v += __shfl_down(v, off);
            if (lane == 0) red[wv][r] = v;
        }
    }
    __syncthreads();
    if (tid < 8)
        out[b0 + tid] = red[0][tid] + red[1][tid] + red[2][tid] + red[3][tid] + v_y_b[0];
}

// ---------------------------------------------------------------------------
extern "C" void kernel_launch(void* const* d_in, const int* in_sizes, int n_in,
                              void* d_out, int out_size, void* d_ws, size_t ws_size,
                              hipStream_t stream)
{
    const float* enc      = (const float*)d_in[0];
    const float* y        = (const float*)d_in[1];
    const float* W_d_w    = (const float*)d_in[2];
    const float* W_d_b    = (const float*)d_in[3];
    const float* U_d_w    = (const float*)d_in[4];
    const float* v_d_w    = (const float*)d_in[5];
    const float* w_tilda_w= (const float*)d_in[6];
    const float* w_tilda_b= (const float*)d_in[7];
    const float* W_y_w    = (const float*)d_in[8];
    const float* W_y_b    = (const float*)d_in[9];
    const float* v_y_w    = (const float*)d_in[10];
    const float* v_y_b    = (const float*)d_in[11];
    const float* W_ih     = (const float*)d_in[12];
    const float* W_hh     = (const float*)d_in[13];
    const float* b_ih     = (const float*)d_in[14];
    const float* b_hh     = (const float*)d_in[15];

    float* out = (float*)d_out;

    unsigned short* Ue_bf  = (unsigned short*)d_ws;              // 33.5M bf16
    unsigned short* enc_bf = Ue_bf + (size_t)BB * TT * MM;       // 33.5M bf16

    // Ue = enc @ U_d^T, stored bf16
    gemm64_bf<<<dim3(BB * TT / 64, MM / 64), 256, 0, stream>>>(
        enc, MM, U_d_w, MM, Ue_bf, MM, MM);

    // enc -> bf16
    cvt_bf16<<<2048, 256, 0, stream>>>(enc, enc_bf, BB * TT * MM / 4);

    // the whole 64-step recurrence + final head
    fused_decoder<<<BB / 8, 512, 0, stream>>>(
        Ue_bf, enc_bf, y, W_d_w, W_d_b, v_d_w, w_tilda_w, w_tilda_b,
        W_ih, W_hh, b_ih, b_hh, W_y_w, W_y_b, v_y_w, v_y_b, out);
}

// Round 5
// 5400.461 us; speedup vs baseline: 1.5366x; 1.2574x over previous
//
#include <hip/hip_runtime.h>
#include <math.h>

#define BB 2048
#define TT 64
#define MM 256

typedef __attribute__((ext_vector_type(8))) unsigned short u16x8;

__device__ __forceinline__ float bf2f(unsigned short u) {
    union { unsigned int i; float f; } v; v.i = ((unsigned int)u) << 16; return v.f;
}
__device__ __forceinline__ unsigned short f2bf(float f) {
    union { float f; unsigned int i; } v; v.f = f;
    const unsigned int r = v.i + 0x7fff + ((v.i >> 16) & 1);  // RNE
    return (unsigned short)(r >> 16);
}

#if __has_builtin(__builtin_amdgcn_exp2f)
#define EXP2F(x) __builtin_amdgcn_exp2f(x)
#else
#define EXP2F(x) __expf((x) * 0.6931471805599453f)
#endif
#if __has_builtin(__builtin_amdgcn_rcpf)
#define RCPF(x) __builtin_amdgcn_rcpf(x)
#else
#define RCPF(x) (1.0f / (x))
#endif

#define TSC 2.885390081777927f  /* 2*log2(e): exp2(TSC*x) = e^(2x) */

// ---------------------------------------------------------------------------
// Tiled GEMM, bf16 output: Ue = enc @ U_d^T
// ---------------------------------------------------------------------------
__global__ __launch_bounds__(256) void gemm64_bf(
    const float* __restrict__ A, int lda,
    const float* __restrict__ W, int ldw,
    unsigned short* __restrict__ C, int ldc, int K)
{
    __shared__ float As[64][36];
    __shared__ float Ws[64][36];

    const int tid = threadIdx.x;
    const int row0 = blockIdx.x * 64;
    const int col0 = blockIdx.y * 64;

    const int lr = tid >> 3;
    const int lc4 = (tid & 7) * 4;
    const int tx = tid & 15;
    const int ty = tid >> 4;

    float acc[4][4] = {{0.f}};

    for (int k0 = 0; k0 < K; k0 += 32) {
        const float4 a0 = *(const float4*)&A[(size_t)(row0 + lr) * lda + k0 + lc4];
        const float4 a1 = *(const float4*)&A[(size_t)(row0 + lr + 32) * lda + k0 + lc4];
        const float4 w0 = *(const float4*)&W[(size_t)(col0 + lr) * ldw + k0 + lc4];
        const float4 w1 = *(const float4*)&W[(size_t)(col0 + lr + 32) * ldw + k0 + lc4];
        *(float4*)&As[lr][lc4] = a0;
        *(float4*)&As[lr + 32][lc4] = a1;
        *(float4*)&Ws[lr][lc4] = w0;
        *(float4*)&Ws[lr + 32][lc4] = w1;
        __syncthreads();

        #pragma unroll
        for (int kk = 0; kk < 32; kk += 4) {
            float4 a[4], w[4];
            #pragma unroll
            for (int i = 0; i < 4; i++) a[i] = *(const float4*)&As[ty + 16 * i][kk];
            #pragma unroll
            for (int j = 0; j < 4; j++) w[j] = *(const float4*)&Ws[tx + 16 * j][kk];
            #pragma unroll
            for (int i = 0; i < 4; i++)
                #pragma unroll
                for (int j = 0; j < 4; j++) {
                    acc[i][j] += a[i].x * w[j].x;
                    acc[i][j] += a[i].y * w[j].y;
                    acc[i][j] += a[i].z * w[j].z;
                    acc[i][j] += a[i].w * w[j].w;
                }
        }
        __syncthreads();
    }

    #pragma unroll
    for (int i = 0; i < 4; i++) {
        const int rr = row0 + ty + 16 * i;
        #pragma unroll
        for (int j = 0; j < 4; j++)
            C[(size_t)rr * ldc + col0 + tx + 16 * j] = f2bf(acc[i][j]);
    }
}

// ---------------------------------------------------------------------------
// q[row] = sum_m w_t_w[m] * enc[row][m]   (row = b*T + t'), one wave per row
// ---------------------------------------------------------------------------
__global__ __launch_bounds__(512) void compute_q(
    const float* __restrict__ enc, const float* __restrict__ w_t_w,
    float* __restrict__ q)
{
    const int row = blockIdx.x * 8 + (threadIdx.x >> 6);
    const int lane = threadIdx.x & 63;
    const float4 e = *(const float4*)&enc[(size_t)row * MM + lane * 4];
    const float4 w = *(const float4*)&w_t_w[lane * 4];
    float s = e.x * w.x + e.y * w.y + e.z * w.z + e.w * w.w;
    #pragma unroll
    for (int off = 32; off > 0; off >>= 1) s += __shfl_down(s, off);
    if (lane == 0) q[row] = s;
}

// ---------------------------------------------------------------------------
// Persistent fused decoder: 256 blocks x 512 threads, block owns 8 batch rows.
// Loop streams ONLY bf16 Ue (L3-resident) + fp32 weights (L2-resident).
// ---------------------------------------------------------------------------
__global__ __launch_bounds__(512) void fused_decoder(
    const unsigned short* __restrict__ Ue,   // [B][T][M] bf16
    const float* __restrict__ enc,           // [B][T][M] fp32
    const float* __restrict__ y,             // [B][T]
    const float* __restrict__ q,             // [B][T] precomputed w~.enc
    const float* __restrict__ W_d_w, const float* __restrict__ W_d_b,
    const float* __restrict__ v_d,
    const float* __restrict__ w_t_w, const float* __restrict__ w_t_b,
    const float* __restrict__ W_ih, const float* __restrict__ W_hh,
    const float* __restrict__ b_ih, const float* __restrict__ b_hh,
    const float* __restrict__ W_y_w, const float* __restrict__ W_y_b,
    const float* __restrict__ v_y_w, const float* __restrict__ v_y_b,
    float* __restrict__ out)                 // [2048 y_Tp1 | 2048*64 beta]
{
    const int tid = threadIdx.x;
    const int b0 = blockIdx.x * 8;
    const int r_a = tid >> 6;       // wave id = local row
    const int t_a = tid & 63;       // lane = t'

    __shared__ __align__(16) float hc[8][512];       // h | c
    __shared__ float gates[8][1024];                 // h @ W_hh^T
    __shared__ __align__(16) float2 xv[8][256];      // (x1*TSC, v_d)
    __shared__ float betas[8][64];                   // last-step beta only
    __shared__ float ytl[8];
    __shared__ __align__(16) float ctx[8][256];
    __shared__ float wihs[1024];
    __shared__ float bsums[1024];
    __shared__ float red[4][8];
    __shared__ float vsum_s;

    // ---- init ----
    float vdn = 0.f, bd = 0.f;
    if (tid < 256) {
        vdn = v_d[tid];
        bd = W_d_b[tid];
        #pragma unroll
        for (int r = 0; r < 8; r++) {
            xv[r][tid] = make_float2(bd * TSC, vdn);   // x1(0) = b_d
            hc[r][tid] = 0.f;
            hc[r][256 + tid] = 0.f;
        }
    }
    for (int i = tid; i < 1024; i += 512) {
        wihs[i] = W_ih[i];
        bsums[i] = b_ih[i] + b_hh[i];
    }
    for (int i = tid; i < 8 * 1024; i += 512) ((float*)gates)[i] = 0.f;

    if (tid < 64) {
        float s = v_d[tid] + v_d[tid + 64] + v_d[tid + 128] + v_d[tid + 192];
        #pragma unroll
        for (int off = 32; off > 0; off >>= 1) s += __shfl_down(s, off);
        if (tid == 0) vsum_s = s;
    }

    const float qreg = q[(size_t)(b0 + r_a) * TT + t_a];
    const float yreg = y[(size_t)(b0 + r_a) * TT + t_a];
    const float wty = w_t_w[256];
    const float wtb = w_t_b[0];

    __syncthreads();
    const float VS = vsum_s;

    const u16x8* __restrict__ uptr =
        (const u16x8*)(Ue + ((size_t)(b0 + r_a) * TT + t_a) * MM);

    for (int t = 0; t < TT; t++) {
        // ---- phase A: l[t'] = VS - 2*sum_m v_m/(e^{2(x1+u)}+1); softmax ----
        float acc = 0.f;
        {
            u16x8 u0 = uptr[0], u1 = uptr[1], u2 = uptr[2], u3 = uptr[3];
            #pragma unroll
            for (int blk = 0; blk < 8; blk++) {
                u16x8 n0, n1, n2, n3;
                if (blk < 7) {
                    n0 = uptr[blk * 4 + 4]; n1 = uptr[blk * 4 + 5];
                    n2 = uptr[blk * 4 + 6]; n3 = uptr[blk * 4 + 7];
                }
                const int mb = blk * 32;
                #define PROC8(uu, mm)                                              \
                    _Pragma("unroll")                                              \
                    for (int j = 0; j < 8; j += 2) {                               \
                        const float4 x2 = *(const float4*)&xv[r_a][(mm) + j];      \
                        const float a0 = fmaf(bf2f(uu[j]),     TSC, x2.x);         \
                        const float a1 = fmaf(bf2f(uu[j + 1]), TSC, x2.z);         \
                        acc = fmaf(x2.y, RCPF(EXP2F(a0) + 1.f), acc);              \
                        acc = fmaf(x2.w, RCPF(EXP2F(a1) + 1.f), acc);              \
                    }
                PROC8(u0, mb)
                PROC8(u1, mb + 8)
                PROC8(u2, mb + 16)
                PROC8(u3, mb + 24)
                #undef PROC8
                u0 = n0; u1 = n1; u2 = n2; u3 = n3;
            }
        }
        const float l = VS - 2.f * acc;

        float mx = l;
        #pragma unroll
        for (int off = 32; off > 0; off >>= 1) mx = fmaxf(mx, __shfl_xor(mx, off));
        const float e = __expf(l - mx);
        float sm = e;
        #pragma unroll
        for (int off = 32; off > 0; off >>= 1) sm += __shfl_xor(sm, off);
        const float bta = e * RCPF(sm);

        if (t == TT - 1) {
            betas[r_a][t_a] = bta;
            out[BB + (size_t)(b0 + r_a) * TT + t_a] = bta;
        }

        // ---- phase B: y_tilda = sum_t' beta*q + wty*y[b][t] + wtb ----
        float part = bta * qreg;
        if (t_a == t) part += fmaf(wty, yreg, wtb);
        #pragma unroll
        for (int off = 32; off > 0; off >>= 1) part += __shfl_down(part, off);
        if (t_a == 0) ytl[r_a] = part;
        __syncthreads();

        // ---- phase C1: LSTM elementwise update ----
        {
            const int p = tid & 255;
            const int half = tid >> 8;
            #pragma unroll
            for (int j = 0; j < 4; j++) {
                const int r = half * 4 + j;
                const float x = ytl[r];
                const float gi = gates[r][p]       + x * wihs[p]       + bsums[p];
                const float gf = gates[r][p + 256] + x * wihs[p + 256] + bsums[p + 256];
                const float gg = gates[r][p + 512] + x * wihs[p + 512] + bsums[p + 512];
                const float go = gates[r][p + 768] + x * wihs[p + 768] + bsums[p + 768];
                const float c_old = hc[r][256 + p];
                const float si = RCPF(1.f + __expf(-gi));
                const float sf = RCPF(1.f + __expf(-gf));
                const float so = RCPF(1.f + __expf(-go));
                const float eg = __expf(2.f * gg);
                const float tg = 1.f - 2.f * RCPF(eg + 1.f);
                const float cn = sf * c_old + si * tg;
                const float ec = __expf(2.f * cn);
                const float tc = 1.f - 2.f * RCPF(ec + 1.f);
                hc[r][p] = so * tc;
                hc[r][256 + p] = cn;
            }
        }
        __syncthreads();

        // ---- phases C2/C3: next x1 and gates (skip at last step) ----
        if (t < TT - 1) {
            if (tid < 256) {
                // x1 col n (K=512) + gate col n (K=256): 6144 FMA
                const int n = tid;
                const float* __restrict__ wr = W_d_w + (size_t)n * 512;
                const float* __restrict__ wg = W_hh + (size_t)n * 256;
                float ax[8] = {0.f, 0.f, 0.f, 0.f, 0.f, 0.f, 0.f, 0.f};
                float ag[8] = {0.f, 0.f, 0.f, 0.f, 0.f, 0.f, 0.f, 0.f};
                #pragma unroll 2
                for (int k = 0; k < 256; k += 4) {
                    const float4 w1 = *(const float4*)(wr + k);
                    const float4 w2 = *(const float4*)(wr + 256 + k);
                    const float4 w3 = *(const float4*)(wg + k);
                    #pragma unroll
                    for (int r = 0; r < 8; r++) {
                        const float4 h4 = *(const float4*)&hc[r][k];
                        const float4 c4 = *(const float4*)&hc[r][256 + k];
                        ax[r] += w1.x * h4.x + w1.y * h4.y + w1.z * h4.z + w1.w * h4.w
                               + w2.x * c4.x + w2.y * c4.y + w2.z * c4.z + w2.w * c4.w;
                        ag[r] += w3.x * h4.x + w3.y * h4.y + w3.z * h4.z + w3.w * h4.w;
                    }
                }
                #pragma unroll
                for (int r = 0; r < 8; r++) {
                    xv[r][n] = make_float2((ax[r] + bd) * TSC, vdn);
                    gates[r][n] = ag[r];
                }
            } else {
                // 3 gate cols (K=256 each): 6144 FMA
                const int n2 = tid - 256;
                const float* __restrict__ wA = W_hh + (size_t)(n2 + 256) * 256;
                const float* __restrict__ wB = W_hh + (size_t)(n2 + 512) * 256;
                const float* __restrict__ wC = W_hh + (size_t)(n2 + 768) * 256;
                float aA[8] = {0.f, 0.f, 0.f, 0.f, 0.f, 0.f, 0.f, 0.f};
                float aB[8] = {0.f, 0.f, 0.f, 0.f, 0.f, 0.f, 0.f, 0.f};
                float aC[8] = {0.f, 0.f, 0.f, 0.f, 0.f, 0.f, 0.f, 0.f};
                #pragma unroll 2
                for (int k = 0; k < 256; k += 4) {
                    const float4 qa = *(const float4*)(wA + k);
                    const float4 qb = *(const float4*)(wB + k);
                    const float4 qc = *(const float4*)(wC + k);
                    #pragma unroll
                    for (int r = 0; r < 8; r++) {
                        const float4 h4 = *(const float4*)&hc[r][k];
                        aA[r] += qa.x * h4.x + qa.y * h4.y + qa.z * h4.z + qa.w * h4.w;
                        aB[r] += qb.x * h4.x + qb.y * h4.y + qb.z * h4.z + qb.w * h4.w;
                        aC[r] += qc.x * h4.x + qc.y * h4.y + qc.z * h4.z + qc.w * h4.w;
                    }
                }
                #pragma unroll
                for (int r = 0; r < 8; r++) {
                    gates[r][n2 + 256] = aA[r];
                    gates[r][n2 + 512] = aB[r];
                    gates[r][n2 + 768] = aC[r];
                }
            }
        }
        __syncthreads();
    }

    // ---- ctx = beta(63) @ enc slice (fp32), per wave its row ----
    {
        const float* __restrict__ ep =
            enc + (size_t)(b0 + r_a) * TT * MM + t_a * 4;
        float c0 = 0.f, c1 = 0.f, c2 = 0.f, c3 = 0.f;
        #pragma unroll 4
        for (int tt2 = 0; tt2 < TT; tt2++) {
            const float4 e4 = *(const float4*)(ep + (size_t)tt2 * MM);
            const float bta = betas[r_a][tt2];
            c0 = fmaf(bta, e4.x, c0);
            c1 = fmaf(bta, e4.y, c1);
            c2 = fmaf(bta, e4.z, c2);
            c3 = fmaf(bta, e4.w, c3);
        }
        ctx[r_a][t_a * 4]     = c0;
        ctx[r_a][t_a * 4 + 1] = c1;
        ctx[r_a][t_a * 4 + 2] = c2;
        ctx[r_a][t_a * 4 + 3] = c3;
    }
    __syncthreads();

    // ---- final head ----
    if (tid < 256) {
        const int n = tid;
        const float* __restrict__ wr = W_y_w + (size_t)n * 512;
        float acc[8] = {0.f, 0.f, 0.f, 0.f, 0.f, 0.f, 0.f, 0.f};
        #pragma unroll 2
        for (int k = 0; k < 256; k += 4) {
            const float4 wh = *(const float4*)(wr + k);
            const float4 wc = *(const float4*)(wr + 256 + k);
            #pragma unroll
            for (int r = 0; r < 8; r++) {
                const float4 h4 = *(const float4*)&hc[r][k];
                const float4 c4 = *(const float4*)&ctx[r][k];
                acc[r] += wh.x * h4.x + wh.y * h4.y + wh.z * h4.z + wh.w * h4.w
                        + wc.x * c4.x + wc.y * c4.y + wc.z * c4.z + wc.w * c4.w;
            }
        }
        const float vy = v_y_w[n];
        const float by = W_y_b[n];
        const int wv = tid >> 6;
        const int lane = tid & 63;
        #pragma unroll
        for (int r = 0; r < 8; r++) {
            float v = (acc[r] + by) * vy;
            #pragma unroll
            for (int off = 32; off > 0; off >>= 1) v += __shfl_down(v, off);
            if (lane == 0) red[wv][r] = v;
        }
    }
    __syncthreads();
    if (tid < 8)
        out[b0 + tid] = red[0][tid] + red[1][tid] + red[2][tid] + red[3][tid] + v_y_b[0];
}

// ---------------------------------------------------------------------------
extern "C" void kernel_launch(void* const* d_in, const int* in_sizes, int n_in,
                              void* d_out, int out_size, void* d_ws, size_t ws_size,
                              hipStream_t stream)
{
    const float* enc      = (const float*)d_in[0];
    const float* y        = (const float*)d_in[1];
    const float* W_d_w    = (const float*)d_in[2];
    const float* W_d_b    = (const float*)d_in[3];
    const float* U_d_w    = (const float*)d_in[4];
    const float* v_d_w    = (const float*)d_in[5];
    const float* w_tilda_w= (const float*)d_in[6];
    const float* w_tilda_b= (const float*)d_in[7];
    const float* W_y_w    = (const float*)d_in[8];
    const float* W_y_b    = (const float*)d_in[9];
    const float* v_y_w    = (const float*)d_in[10];
    const float* v_y_b    = (const float*)d_in[11];
    const float* W_ih     = (const float*)d_in[12];
    const float* W_hh     = (const float*)d_in[13];
    const float* b_ih     = (const float*)d_in[14];
    const float* b_hh     = (const float*)d_in[15];

    float* out = (float*)d_out;

    unsigned short* Ue_bf = (unsigned short*)d_ws;            // 33.5M bf16
    float* qbuf = (float*)(Ue_bf + (size_t)BB * TT * MM);     // 131072 fp32

    // Ue = enc @ U_d^T, stored bf16
    gemm64_bf<<<dim3(BB * TT / 64, MM / 64), 256, 0, stream>>>(
        enc, MM, U_d_w, MM, Ue_bf, MM, MM);

    // q = enc . w_tilda (step-invariant part of y_tilda)
    compute_q<<<BB * TT / 8, 512, 0, stream>>>(enc, w_tilda_w, qbuf);

    // the whole 64-step recurrence + final head
    fused_decoder<<<BB / 8, 512, 0, stream>>>(
        Ue_bf, enc, y, qbuf, W_d_w, W_d_b, v_d_w, w_tilda_w, w_tilda_b,
        W_ih, W_hh, b_ih, b_hh, W_y_w, W_y_b, v_y_w, v_y_b, out);
}